// Round 2
// baseline (1065.670 us; speedup 1.0000x reference)
//
#include <hip/hip_runtime.h>
#include <math.h>

#define NB   8192
#define NTOK 21
#define DM   128
#define NP   10
#define NS   11
#define NH   2
#define DH   64
#define D2   32
#define QS   388   // qkv LDS row stride in floats: 16B-aligned rows (388%4==0)

// ---------------- kernel 1: per-patch-row norms of zc-rmsnorm(x) ----------------
__global__ __launch_bounds__(256) void k_norms(const float* __restrict__ x,
                                               const float* __restrict__ g,
                                               float* __restrict__ norms)
{
    const int wave = threadIdx.x >> 6;
    const int lane = threadIdx.x & 63;
    const int row = blockIdx.x * 4 + wave;           // 0 .. NB*NP-1
    if (row >= NB * NP) return;
    const int b = row / NP, p = row - b * NP;
    const float* xr = x + (size_t)b * (NTOK * DM) + (2 * p + 1) * DM;
    float a0 = xr[lane], a1 = xr[lane + 64];
    float s = a0 + a1, sq = a0 * a0 + a1 * a1;
    #pragma unroll
    for (int off = 32; off; off >>= 1) { s += __shfl_xor(s, off); sq += __shfl_xor(sq, off); }
    float mean = s * (1.0f / DM);
    float rstd = rsqrtf(sq * (1.0f / DM) - mean * mean + 1e-8f);
    float h0 = (a0 - mean) * rstd * g[lane];
    float h1 = (a1 - mean) * rstd * g[lane + 64];
    float n2 = h0 * h0 + h1 * h1;
    #pragma unroll
    for (int off = 32; off; off >>= 1) n2 += __shfl_xor(n2, off);
    if (lane == 0) norms[row] = sqrtf(n2);
}

// ---------------- kernel 2: deterministic mean of 81920 norms ----------------
__global__ __launch_bounds__(256) void k_mean(const float* __restrict__ norms,
                                              float* __restrict__ meanp)
{
    __shared__ float sdata[4];
    float s = 0.f;
    for (int i = threadIdx.x; i < NB * NP; i += 256) s += norms[i];
    #pragma unroll
    for (int off = 32; off; off >>= 1) s += __shfl_xor(s, off);
    const int wave = threadIdx.x >> 6, lane = threadIdx.x & 63;
    if (lane == 0) sdata[wave] = s;
    __syncthreads();
    if (threadIdx.x == 0)
        meanp[0] = (sdata[0] + sdata[1] + sdata[2] + sdata[3]) * (1.0f / (NB * NP));
}

// ---------------- kernel 3: fully fused per-batch pipeline ----------------
__global__ __launch_bounds__(256) void k_main(
    const float* __restrict__ x,   const float* __restrict__ fcr,
    const float* __restrict__ fci, const float* __restrict__ g,
    const float* __restrict__ Wqkv, const float* __restrict__ bqkv,
    const float* __restrict__ Wout, const float* __restrict__ bout,
    const float* __restrict__ Wg,   const float* __restrict__ bg,
    const float* __restrict__ Wr,   const float* __restrict__ br,
    const float* __restrict__ Bb,   const float* __restrict__ meanp,
    float* __restrict__ out)
{
    __shared__ float xs[NTOK][DM];        // 10.5 KB: residual
    __shared__ float hs[NTOK][DM];        // 10.5 KB: normed
    __shared__ float qkv[NTOK][QS];       // 31.8 KB: q(0:128)|k(128:256)|v(256:384); q slot reused for y
    __shared__ float att[NH][NTOK][NTOK + 1];   // 3.7 KB
    __shared__ float att2[NH][NP][NS + 1];      // 1.0 KB
    __shared__ float y2b[NP][DM];         // 5.0 KB
    __shared__ float normv[NP];
    // total ~63.9 KB -> 2 blocks/CU

    const int tid = threadIdx.x;
    const int b = blockIdx.x;
    const float* xb = x + (size_t)b * (NTOK * DM);

    // P0: stage x
    {
        const float4* src = (const float4*)xb;
        float4* dst = (float4*)&xs[0][0];
        for (int i = tid; i < NTOK * DM / 4; i += 256) dst[i] = src[i];
    }
    __syncthreads();

    // P1: zero-centered rmsnorm -> hs; patch-row norms -> normv
    {
        const int wave = tid >> 6, lane = tid & 63;
        for (int r = wave; r < NTOK; r += 4) {
            float a0 = xs[r][lane], a1 = xs[r][lane + 64];
            float s = a0 + a1, sq = a0 * a0 + a1 * a1;
            #pragma unroll
            for (int off = 32; off; off >>= 1) { s += __shfl_xor(s, off); sq += __shfl_xor(sq, off); }
            float mean = s * (1.0f / DM);
            float rstd = rsqrtf(sq * (1.0f / DM) - mean * mean + 1e-8f);
            float h0 = (a0 - mean) * rstd * g[lane];
            float h1 = (a1 - mean) * rstd * g[lane + 64];
            hs[r][lane] = h0; hs[r][lane + 64] = h1;
            if (r & 1) {
                float n2 = h0 * h0 + h1 * h1;
                #pragma unroll
                for (int off = 32; off; off >>= 1) n2 += __shfl_xor(n2, off);
                if (lane == 0) normv[r >> 1] = sqrtf(n2);
            }
        }
    }
    __syncthreads();

    // P2: qkv = hs @ Wqkv + bqkv.  thread owns col n0=tid; tids<128 also own n1=256+tid.
    if (tid < 128) {
        float acc0[NTOK], acc1[NTOK];
        #pragma unroll
        for (int r = 0; r < NTOK; r++) { acc0[r] = 0.f; acc1[r] = 0.f; }
        const int n0 = tid, n1 = 256 + tid;
        for (int k = 0; k < DM; k += 4) {
            float w00 = Wqkv[(k + 0) * 384 + n0];
            float w01 = Wqkv[(k + 1) * 384 + n0];
            float w02 = Wqkv[(k + 2) * 384 + n0];
            float w03 = Wqkv[(k + 3) * 384 + n0];
            float w10 = Wqkv[(k + 0) * 384 + n1];
            float w11 = Wqkv[(k + 1) * 384 + n1];
            float w12 = Wqkv[(k + 2) * 384 + n1];
            float w13 = Wqkv[(k + 3) * 384 + n1];
            #pragma unroll
            for (int r = 0; r < NTOK; r++) {
                float4 h4 = *(const float4*)&hs[r][k];
                acc0[r] += h4.x * w00 + h4.y * w01 + h4.z * w02 + h4.w * w03;
                acc1[r] += h4.x * w10 + h4.y * w11 + h4.z * w12 + h4.w * w13;
            }
        }
        const float b0 = bqkv[n0], b1 = bqkv[n1];
        #pragma unroll
        for (int r = 0; r < NTOK; r++) { qkv[r][n0] = acc0[r] + b0; qkv[r][n1] = acc1[r] + b1; }
    } else {
        float acc0[NTOK];
        #pragma unroll
        for (int r = 0; r < NTOK; r++) acc0[r] = 0.f;
        const int n0 = tid;
        for (int k = 0; k < DM; k += 4) {
            float w00 = Wqkv[(k + 0) * 384 + n0];
            float w01 = Wqkv[(k + 1) * 384 + n0];
            float w02 = Wqkv[(k + 2) * 384 + n0];
            float w03 = Wqkv[(k + 3) * 384 + n0];
            #pragma unroll
            for (int r = 0; r < NTOK; r++) {
                float4 h4 = *(const float4*)&hs[r][k];
                acc0[r] += h4.x * w00 + h4.y * w01 + h4.z * w02 + h4.w * w03;
            }
        }
        const float b0 = bqkv[n0];
        #pragma unroll
        for (int r = 0; r < NTOK; r++) qkv[r][n0] = acc0[r] + b0;
    }
    __syncthreads();

    // P3: RoPE on q and k (pairs within each head's 64 dims)
    for (int i = tid; i < NTOK * 128; i += 256) {
        int r = i >> 7, p = i & 127;
        int which = p >> 6, hd = (p >> 5) & 1, j = p & 31;
        int col = which * 128 + hd * 64 + 2 * j;
        float fr = fcr[r * D2 + j], fi = fci[r * D2 + j];
        float a = qkv[r][col], c2 = qkv[r][col + 1];
        qkv[r][col]     = a * fr - c2 * fi;
        qkv[r][col + 1] = a * fi + c2 * fr;
    }
    __syncthreads();

    // P4: attention scores (full, with bias) and patch/stat scores
    {
        const float scale = 0.125f;  // 1/sqrt(64)
        for (int o = tid; o < NH * NTOK * NTOK; o += 256) {
            int hh = o / (NTOK * NTOK);
            int rem = o - hh * (NTOK * NTOK);
            int n = rem / NTOK, m = rem - n * NTOK;
            float s = 0.f;
            #pragma unroll
            for (int d = 0; d < DH; d++) s += qkv[n][hh * DH + d] * qkv[m][128 + hh * DH + d];
            att[hh][n][m] = s * scale + Bb[n * NTOK + m];
        }
        for (int o = tid; o < NH * NP * NS; o += 256) {
            int hh = o / (NP * NS);
            int rem = o - hh * (NP * NS);
            int p = rem / NS, ss2 = rem - p * NS;
            int qr = 2 * p + 1, kr = 2 * ss2;
            float s = 0.f;
            #pragma unroll
            for (int d = 0; d < DH; d++) s += qkv[qr][hh * DH + d] * qkv[kr][128 + hh * DH + d];
            att2[hh][p][ss2] = s * scale;
        }
    }
    __syncthreads();

    // P5: softmax rows (42 full-attn rows; 20 patch-attn rows)
    if (tid < NH * NTOK) {
        int hh = tid / NTOK, n = tid - hh * NTOK;
        float mx = -1e30f;
        for (int m = 0; m < NTOK; m++) mx = fmaxf(mx, att[hh][n][m]);
        float s = 0.f;
        for (int m = 0; m < NTOK; m++) { float e = expf(att[hh][n][m] - mx); att[hh][n][m] = e; s += e; }
        float inv = 1.0f / s;
        for (int m = 0; m < NTOK; m++) att[hh][n][m] *= inv;
    } else if (tid >= 64 && tid < 64 + NH * NP) {
        int t2 = tid - 64;
        int hh = t2 / NP, p = t2 - hh * NP;
        float mx = -1e30f;
        for (int m = 0; m < NS; m++) mx = fmaxf(mx, att2[hh][p][m]);
        float s = 0.f;
        for (int m = 0; m < NS; m++) { float e = expf(att2[hh][p][m] - mx); att2[hh][p][m] = e; s += e; }
        float inv = 1.0f / s;
        for (int m = 0; m < NS; m++) att2[hh][p][m] *= inv;
    }
    __syncthreads();

    // P6: y = att @ v  (written into dead q slot);  y2 = att2 @ v_stat
    {
        const int half = tid >> 7, c = tid & 127;
        const int hh = c >> 6;
        const int r0 = half * 11, r1 = half ? NTOK : 11;
        for (int r = r0; r < r1; r++) {
            float s = 0.f;
            #pragma unroll
            for (int m = 0; m < NTOK; m++) s += att[hh][r][m] * qkv[m][256 + c];
            qkv[r][c] = s;   // q region is dead after P4 -> holds y now
        }
        const int p0 = half * 5;
        for (int p = p0; p < p0 + 5; p++) {
            float s = 0.f;
            #pragma unroll
            for (int m = 0; m < NS; m++) s += att2[hh][p][m] * qkv[2 * m][256 + c];
            y2b[p][c] = s;
        }
    }
    __syncthreads();

    // P7: out = x + y@Wout + bout (+ patch rows: u * sigmoid(h@Wg+bg) * (y2@Wr+br))
    {
        const int half = tid >> 7, c = tid & 127;
        const int r0 = half * 11;
        const int nr = half ? 10 : 11;
        const int p0 = half * 5;
        float acc[11], ag[5], ar[5];
        #pragma unroll
        for (int i = 0; i < 11; i++) acc[i] = 0.f;
        #pragma unroll
        for (int i = 0; i < 5; i++) { ag[i] = 0.f; ar[i] = 0.f; }
        for (int k = 0; k < DM; k += 4) {
            float o0 = Wout[(k + 0) * DM + c], o1 = Wout[(k + 1) * DM + c];
            float o2 = Wout[(k + 2) * DM + c], o3 = Wout[(k + 3) * DM + c];
            #pragma unroll
            for (int i = 0; i < 11; i++) {
                int r = r0 + i; r = r > 20 ? 20 : r;     // half1 i=10 duplicates row20 (store masked)
                float4 y4 = *(const float4*)&qkv[r][k];
                acc[i] += y4.x * o0 + y4.y * o1 + y4.z * o2 + y4.w * o3;
            }
            float g0 = Wg[(k + 0) * DM + c], g1 = Wg[(k + 1) * DM + c];
            float g2 = Wg[(k + 2) * DM + c], g3 = Wg[(k + 3) * DM + c];
            float q0 = Wr[(k + 0) * DM + c], q1 = Wr[(k + 1) * DM + c];
            float q2 = Wr[(k + 2) * DM + c], q3 = Wr[(k + 3) * DM + c];
            #pragma unroll
            for (int i = 0; i < 5; i++) {
                int pr = 2 * (p0 + i) + 1;
                float4 h4 = *(const float4*)&hs[pr][k];
                ag[i] += h4.x * g0 + h4.y * g1 + h4.z * g2 + h4.w * g3;
                float4 v4 = *(const float4*)&y2b[p0 + i][k];
                ar[i] += v4.x * q0 + v4.y * q1 + v4.z * q2 + v4.w * q3;
            }
        }
        const float mn = meanp[0];
        const float bo = bout[c], bgc = bg[c], brc = br[c];
        float gy[5];
        #pragma unroll
        for (int i = 0; i < 5; i++) {
            float gate = 1.0f / (1.0f + expf(-(ag[i] + bgc)));
            float u = 1.0f - 1.0f / (1.0f + expf(-(normv[p0 + i] - mn)));
            gy[i] = u * gate * (ar[i] + brc);
        }
        float* ob = out + (size_t)b * (NTOK * DM);
        #pragma unroll
        for (int i = 0; i < 11; i++) {
            if (i < nr) {
                int r = r0 + i;
                float v = xs[r][c] + acc[i] + bo;
                if (r & 1) v += gy[i >> 1];
                ob[r * DM + c] = v;
            }
        }
    }
}

extern "C" void kernel_launch(void* const* d_in, const int* in_sizes, int n_in,
                              void* d_out, int out_size, void* d_ws, size_t ws_size,
                              hipStream_t stream)
{
    (void)in_sizes; (void)n_in; (void)out_size; (void)ws_size;
    const float* x    = (const float*)d_in[0];
    const float* fcr  = (const float*)d_in[1];
    const float* fci  = (const float*)d_in[2];
    const float* g    = (const float*)d_in[3];
    const float* Wqkv = (const float*)d_in[4];
    const float* bqkv = (const float*)d_in[5];
    const float* Wout = (const float*)d_in[6];
    const float* bout = (const float*)d_in[7];
    const float* Wg   = (const float*)d_in[8];
    const float* bg   = (const float*)d_in[9];
    const float* Wr   = (const float*)d_in[10];
    const float* br   = (const float*)d_in[11];
    const float* Bb   = (const float*)d_in[12];
    float* out = (float*)d_out;

    float* ws    = (float*)d_ws;
    float* meanp = ws;          // 1 float
    float* norms = ws + 64;     // NB*NP floats (328 KB total — well within ws)

    hipLaunchKernelGGL(k_norms, dim3((NB * NP) / 4), dim3(256), 0, stream, x, g, norms);
    hipLaunchKernelGGL(k_mean,  dim3(1), dim3(256), 0, stream, norms, meanp);
    hipLaunchKernelGGL(k_main,  dim3(NB), dim3(256), 0, stream,
                       x, fcr, fci, g, Wqkv, bqkv, Wout, bout, Wg, bg, Wr, br, Bb, meanp, out);
}

// Round 4
// 479.349 us; speedup vs baseline: 2.2232x; 2.2232x over previous
//
#include <hip/hip_runtime.h>
#include <math.h>

#define NB   8192
#define NTOK 21
#define NP   10

typedef __bf16 bf16_t;
typedef __bf16 bf16x8 __attribute__((ext_vector_type(8)));
typedef __bf16 bf16x4 __attribute__((ext_vector_type(4)));
typedef float  f32x4  __attribute__((ext_vector_type(4)));

// swizzled element-index helpers (bf16 units; XOR at 8-element = 16B granularity)
#define ROW128(r,c) ((r)*128 + ((c) ^ (((r)&7)<<3)))   // [32][128] tiles, 256B rows
#define VTIDX(d,m)  ((d)*32  + ((m) ^ (((d)&3)<<3)))   // vt [128][32], 64B rows
#define ATIDX(r,m)  ((r)*32  + ((m) ^ (((r)&3)<<3)))   // attb rows, 64B rows

#define MFMA(a,b,c) __builtin_amdgcn_mfma_f32_16x16x32_bf16((a),(b),(c),0,0,0)

// ---------------- kernel 0: weights -> bf16, B-fragment layout [k>>3][n][8] ----------------
__global__ __launch_bounds__(256) void k_wconv(
    const float* __restrict__ Wqkv, const float* __restrict__ Wout,
    const float* __restrict__ Wg,   const float* __restrict__ Wr,
    bf16_t* __restrict__ wq, bf16_t* __restrict__ wo,
    bf16_t* __restrict__ wgb, bf16_t* __restrict__ wrb)
{
    int i = blockIdx.x * 256 + threadIdx.x;           // 0 .. 98303
    if (i < 49152) {
        int k = i / 384, n = i - k * 384;
        wq[((k >> 3) * 384 + n) * 8 + (k & 7)] = (bf16_t)Wqkv[i];
    } else {
        int j = i - 49152;
        int sel = j >> 14;                            // 0=Wout 1=Wg 2=Wr
        int t = j & 16383;
        int k = t >> 7, n = t & 127;
        const float* src = sel == 0 ? Wout : (sel == 1 ? Wg : Wr);
        bf16_t* dst = sel == 0 ? wo : (sel == 1 ? wgb : wrb);
        dst[((k >> 3) * 128 + n) * 8 + (k & 7)] = (bf16_t)src[t];
    }
}

// ---------------- kernel 1: per-patch-row norms of zc-rmsnorm(x) ----------------
__global__ __launch_bounds__(256) void k_norms(const float* __restrict__ x,
                                               const float* __restrict__ g,
                                               float* __restrict__ norms)
{
    const int wave = threadIdx.x >> 6;
    const int lane = threadIdx.x & 63;
    const int row = blockIdx.x * 4 + wave;            // 0 .. NB*NP-1
    if (row >= NB * NP) return;
    const int b = row / NP, p = row - b * NP;
    const float* xr = x + (size_t)b * (NTOK * 128) + (2 * p + 1) * 128;
    float a0 = xr[lane], a1 = xr[lane + 64];
    float s = a0 + a1, sq = a0 * a0 + a1 * a1;
    #pragma unroll
    for (int off = 32; off; off >>= 1) { s += __shfl_xor(s, off); sq += __shfl_xor(sq, off); }
    float mean = s * (1.0f / 128);
    float rstd = rsqrtf(sq * (1.0f / 128) - mean * mean + 1e-8f);
    float h0 = (a0 - mean) * rstd * g[lane];
    float h1 = (a1 - mean) * rstd * g[lane + 64];
    float n2 = h0 * h0 + h1 * h1;
    #pragma unroll
    for (int off = 32; off; off >>= 1) n2 += __shfl_xor(n2, off);
    if (lane == 0) norms[row] = sqrtf(n2);
}

// ---------------- kernel 2: mean via per-block reduce + one atomic ----------------
__global__ __launch_bounds__(256) void k_mean(const float* __restrict__ norms,
                                              float* __restrict__ meanp)
{
    __shared__ float sd[4];
    int base = blockIdx.x * 1024 + threadIdx.x;
    float s = norms[base] + norms[base + 256] + norms[base + 512] + norms[base + 768];
    #pragma unroll
    for (int off = 32; off; off >>= 1) s += __shfl_xor(s, off);
    int w = threadIdx.x >> 6, l = threadIdx.x & 63;
    if (l == 0) sd[w] = s;
    __syncthreads();
    if (threadIdx.x == 0) atomicAdd(meanp, sd[0] + sd[1] + sd[2] + sd[3]);  // meanp holds SUM
}

// ---------------- kernel 3: fused per-batch pipeline, bf16 MFMA ----------------
__global__ __launch_bounds__(256) void k_main(
    const float* __restrict__ x,   const float* __restrict__ fcr,
    const float* __restrict__ fci, const float* __restrict__ g,
    const float* __restrict__ bqkv, const float* __restrict__ bout,
    const float* __restrict__ bg,   const float* __restrict__ br,
    const float* __restrict__ Bb,   const float* __restrict__ meanp,
    const bf16_t* __restrict__ wq,  const bf16_t* __restrict__ wo,
    const bf16_t* __restrict__ wgb, const bf16_t* __restrict__ wrb,
    float* __restrict__ out)
{
    __shared__ __align__(16) float  xs[21 * 128];       // residual (10.5K)
    __shared__ __align__(16) bf16_t hsb[32 * 128];      // normed, bf16, swz; rows 21-31 = 0 (8K)
    __shared__ __align__(16) float  fcs[21 * 32];       // rope cos (2.6K)
    __shared__ __align__(16) float  fis[21 * 32];       // rope sin (2.6K)
    __shared__ __align__(16) bf16_t reg1[32 * 128];     // qb -> attb[2][32][32] + att2e[2][16][32] (8K)
    __shared__ __align__(16) bf16_t reg2[32 * 128];     // kb -> yb (8K)
    __shared__ __align__(16) bf16_t reg3[128 * 32];     // vt[d][m] -> gyb f32[16][128] (8K)
    __shared__ float att [2 * 21 * 24];                 // scores f32 (4K)
    __shared__ float att2[2 * 10 * 12];                 // patch scores f32 (1K)
    __shared__ __align__(16) bf16_t y2bb[16 * 128];     // y2, bf16, swz (4K)
    __shared__ float normv[10];
    // total ~57 KB -> 2 blocks/CU

    const int tid = threadIdx.x;
    const int w = tid >> 6, l = tid & 63, l15 = l & 15, gq = l >> 4;
    const int b = blockIdx.x;
    const float* xb = x + (size_t)b * (21 * 128);

    // ---- P0: stage x, rope tables; zero hsb pad rows ----
    {
        const float4* s4 = (const float4*)xb;  float4* d4 = (float4*)xs;
        for (int i = tid; i < 672; i += 256) d4[i] = s4[i];
        const float4* c4 = (const float4*)fcr; float4* dc = (float4*)fcs;
        const float4* i4 = (const float4*)fci; float4* di = (float4*)fis;
        if (tid < 168) { dc[tid] = c4[tid]; di[tid] = i4[tid]; }
        for (int i = tid; i < 11 * 128; i += 256)
            hsb[(21 + (i >> 7)) * 128 + (i & 127)] = (bf16_t)0.f;
    }
    __syncthreads();

    // ---- P1: zc-rmsnorm -> hsb (bf16, swz); patch norms -> normv ----
    for (int r = w; r < 21; r += 4) {
        float a0 = xs[r * 128 + l], a1 = xs[r * 128 + 64 + l];
        float s = a0 + a1, sq = a0 * a0 + a1 * a1;
        #pragma unroll
        for (int off = 32; off; off >>= 1) { s += __shfl_xor(s, off); sq += __shfl_xor(sq, off); }
        float mean = s * (1.0f / 128);
        float rstd = rsqrtf(sq * (1.0f / 128) - mean * mean + 1e-8f);
        float h0 = (a0 - mean) * rstd * g[l];
        float h1 = (a1 - mean) * rstd * g[l + 64];
        hsb[ROW128(r, l)]      = (bf16_t)h0;
        hsb[ROW128(r, l + 64)] = (bf16_t)h1;
        if (r & 1) {
            float n2 = h0 * h0 + h1 * h1;
            #pragma unroll
            for (int off = 32; off; off >>= 1) n2 += __shfl_xor(n2, off);
            if (l == 0) normv[r >> 1] = sqrtf(n2);
        }
    }
    __syncthreads();

    // ---- P2: qkv = h @ Wqkv + b (MFMA); rope q/k in-reg; scatter q->qb k->kb v->vt ----
    {
        bf16x8 afr[2][4];
        #pragma unroll
        for (int mt = 0; mt < 2; mt++)
            #pragma unroll
            for (int ks = 0; ks < 4; ks++)
                afr[mt][ks] = *(const bf16x8*)&hsb[ROW128(mt * 16 + l15, ks * 32 + gq * 8)];
        for (int nt = w * 6; nt < w * 6 + 6; ++nt) {
            int n = nt * 16 + l15;
            bf16x8 bfr[4];
            #pragma unroll
            for (int ks = 0; ks < 4; ks++)
                bfr[ks] = *(const bf16x8*)&wq[((ks * 4 + gq) * 384 + n) * 8];
            float bias = bqkv[n];
            #pragma unroll
            for (int mt = 0; mt < 2; mt++) {
                f32x4 acc = {0.f, 0.f, 0.f, 0.f};
                #pragma unroll
                for (int ks = 0; ks < 4; ks++) acc = MFMA(afr[mt][ks], bfr[ks], acc);
                int rbase = mt * 16 + gq * 4;
                if (n < 256) {                       // q or k: rope then store bf16
                    int d = n & 63, j = d >> 1;
                    bool ev = !(d & 1);
                    bf16_t* dst = (n < 128) ? reg1 : reg2;
                    int cc = n & 127;
                    #pragma unroll
                    for (int i = 0; i < 4; i++) {
                        int r = rbase + i; int rr = r < 21 ? r : 0;
                        float v = acc[i] + bias;
                        float p = __shfl_xor(v, 1);  // partner holds the other half of the pair
                        float fr = fcs[rr * 32 + j], fi = fis[rr * 32 + j];
                        float o = ev ? (v * fr - p * fi) : (p * fi + v * fr);
                        dst[ROW128(r, cc)] = (bf16_t)o;
                    }
                } else {                             // v: store transposed vt[d][m]
                    int d = n - 256;
                    bf16x4 pv;
                    #pragma unroll
                    for (int i = 0; i < 4; i++) pv[i] = (bf16_t)(acc[i] + bias);
                    *(bf16x4*)&reg3[VTIDX(d, rbase)] = pv;
                }
            }
        }
    }
    __syncthreads();

    // ---- P4: scores via MFMA: att = qb @ kb^T * 0.125 + Bb; att2 patch/stat ----
    {
        #pragma unroll
        for (int q2 = 0; q2 < 2; q2++) {
            int t = w * 2 + q2;                       // 8 full tiles
            int hh = t >> 2, mt = (t >> 1) & 1, nt = t & 1;
            f32x4 acc = {0.f, 0.f, 0.f, 0.f};
            #pragma unroll
            for (int ks = 0; ks < 2; ks++) {
                bf16x8 a  = *(const bf16x8*)&reg1[ROW128(mt * 16 + l15, hh * 64 + ks * 32 + gq * 8)];
                bf16x8 bb = *(const bf16x8*)&reg2[ROW128(nt * 16 + l15, hh * 64 + ks * 32 + gq * 8)];
                acc = MFMA(a, bb, acc);
            }
            int m = nt * 16 + l15;
            if (m < 21) {
                #pragma unroll
                for (int i = 0; i < 4; i++) {
                    int n = mt * 16 + gq * 4 + i;
                    if (n < 21) att[hh * 504 + n * 24 + m] = acc[i] * 0.125f + Bb[n * 21 + m];
                }
            }
        }
        if (w < 2) {                                  // 2 patch tiles (head = w)
            int hh = w;
            int ra = 2 * l15 + 1; if (ra > 20) ra = 20;
            int rb = 2 * l15;     if (rb > 20) rb = 20;
            f32x4 acc = {0.f, 0.f, 0.f, 0.f};
            #pragma unroll
            for (int ks = 0; ks < 2; ks++) {
                bf16x8 a  = *(const bf16x8*)&reg1[ROW128(ra, hh * 64 + ks * 32 + gq * 8)];
                bf16x8 bb = *(const bf16x8*)&reg2[ROW128(rb, hh * 64 + ks * 32 + gq * 8)];
                acc = MFMA(a, bb, acc);
            }
            int s = l15;
            if (s < 11) {
                #pragma unroll
                for (int i = 0; i < 4; i++) {
                    int p = gq * 4 + i;
                    if (p < 10) att2[hh * 120 + p * 12 + s] = acc[i] * 0.125f;
                }
            }
        }
    }
    __syncthreads();

    // ---- P5: softmax rows (fp32) ----
    if (tid < 42) {
        int hh = tid / 21, n = tid - hh * 21;
        float* row = &att[hh * 504 + n * 24];
        float mx = -1e30f;
        for (int m = 0; m < 21; m++) mx = fmaxf(mx, row[m]);
        float s = 0.f;
        for (int m = 0; m < 21; m++) { float e = __expf(row[m] - mx); row[m] = e; s += e; }
        float inv = 1.f / s;
        for (int m = 0; m < 21; m++) row[m] *= inv;
    } else if (tid >= 64 && tid < 84) {
        int t2 = tid - 64, hh = t2 / 10, p = t2 - hh * 10;
        float* row = &att2[hh * 120 + p * 12];
        float mx = -1e30f;
        for (int m = 0; m < 11; m++) mx = fmaxf(mx, row[m]);
        float s = 0.f;
        for (int m = 0; m < 11; m++) { float e = __expf(row[m] - mx); row[m] = e; s += e; }
        float inv = 1.f / s;
        for (int m = 0; m < 11; m++) row[m] *= inv;
    }
    __syncthreads();

    // ---- P5b: probs -> bf16 fragments (attb in qb region; att2e expanded to full keys) ----
    {
        bf16_t* attb  = reg1;            // [2][32][32], zero-padded
        bf16_t* att2e = reg1 + 2048;     // [2][16][32]: col m even -> att2[p][m/2], else 0
        for (int i = tid; i < 2048; i += 256) {
            int hh = i >> 10, r = (i >> 5) & 31, m = i & 31;
            float v = (r < 21 && m < 21) ? att[hh * 504 + r * 24 + m] : 0.f;
            attb[hh * 1024 + ATIDX(r, m)] = (bf16_t)v;
        }
        for (int i = tid; i < 1024; i += 256) {
            int hh = i >> 9, p = (i >> 5) & 15, m = i & 31;
            float v = (p < 10 && m < 21 && !(m & 1)) ? att2[hh * 120 + p * 12 + (m >> 1)] : 0.f;
            att2e[hh * 512 + ATIDX(p, m)] = (bf16_t)v;
        }
    }
    __syncthreads();

    // ---- P6: y = attb @ v (into yb = kb region); y2 = att2e @ v (into y2bb) ----
    {
        bf16_t* attb  = reg1;
        bf16_t* att2e = reg1 + 2048;
        for (int t = w * 6; t < w * 6 + 6; ++t) {     // 24 tiles: 16 y + 8 y2
            int hh, dloc, mt = 0, isY2;
            if (t < 16) { hh = t >> 3; mt = (t >> 2) & 1; dloc = hh * 64 + (t & 3) * 16 + l15; isY2 = 0; }
            else        { int u = t - 16; hh = u >> 2;    dloc = hh * 64 + (u & 3) * 16 + l15; isY2 = 1; }
            bf16x8 a;
            if (!isY2) { int r = mt * 16 + l15; a = *(const bf16x8*)&attb[hh * 1024 + ATIDX(r, gq * 8)]; }
            else       {                        a = *(const bf16x8*)&att2e[hh * 512 + ATIDX(l15, gq * 8)]; }
            bf16x8 bb = *(const bf16x8*)&reg3[VTIDX(dloc, gq * 8)];
            f32x4 acc = {0.f, 0.f, 0.f, 0.f};
            acc = MFMA(a, bb, acc);
            if (!isY2) {
                #pragma unroll
                for (int i = 0; i < 4; i++) reg2[ROW128(mt * 16 + gq * 4 + i, dloc)] = (bf16_t)acc[i];
            } else {
                #pragma unroll
                for (int i = 0; i < 4; i++) y2bb[ROW128(gq * 4 + i, dloc)] = (bf16_t)acc[i];
            }
        }
    }
    __syncthreads();

    // ---- P7a: gate & refine GEMMs; gy -> gyb (vt region, now dead) ----
    {
        float mn = meanp[0] * (1.f / 81920.f);
        float* gyb = (float*)reg3;
        #pragma unroll
        for (int q2 = 0; q2 < 2; q2++) {
            int nt = w * 2 + q2;
            int n = nt * 16 + l15;
            f32x4 accg = {0.f, 0.f, 0.f, 0.f}, accr = {0.f, 0.f, 0.f, 0.f};
            #pragma unroll
            for (int ks = 0; ks < 4; ks++) {
                bf16x8 wgf = *(const bf16x8*)&wgb[((ks * 4 + gq) * 128 + n) * 8];
                bf16x8 wrf = *(const bf16x8*)&wrb[((ks * 4 + gq) * 128 + n) * 8];
                bf16x8 ha  = *(const bf16x8*)&hsb[ROW128(2 * l15 + 1, ks * 32 + gq * 8)];
                bf16x8 ya  = *(const bf16x8*)&y2bb[ROW128(l15, ks * 32 + gq * 8)];
                accg = MFMA(ha, wgf, accg);
                accr = MFMA(ya, wrf, accr);
            }
            float bgc = bg[n], brc = br[n];
            #pragma unroll
            for (int i = 0; i < 4; i++) {
                int p = gq * 4 + i;
                float nv = normv[p < 10 ? p : 0];
                float gate = 1.f / (1.f + __expf(-(accg[i] + bgc)));
                float u = 1.f - 1.f / (1.f + __expf(-(nv - mn)));
                gyb[p * 128 + n] = (p < 10) ? u * gate * (accr[i] + brc) : 0.f;
            }
        }
    }
    __syncthreads();

    // ---- P7b: out = x + y @ Wout + bout (+ gy on patch rows) ----
    {
        float* gyb = (float*)reg3;
        float* ob = out + (size_t)b * 2688;
        for (int t = w * 4; t < w * 4 + 4; ++t) {     // 16 tiles
            int mt = t >> 3, nt = t & 7;
            int n = nt * 16 + l15;
            f32x4 acc = {0.f, 0.f, 0.f, 0.f};
            #pragma unroll
            for (int ks = 0; ks < 4; ks++) {
                bf16x8 a  = *(const bf16x8*)&reg2[ROW128(mt * 16 + l15, ks * 32 + gq * 8)];
                bf16x8 wf = *(const bf16x8*)&wo[((ks * 4 + gq) * 128 + n) * 8];
                acc = MFMA(a, wf, acc);
            }
            float bo = bout[n];
            #pragma unroll
            for (int i = 0; i < 4; i++) {
                int r = mt * 16 + gq * 4 + i;
                if (r < 21) {
                    float v = xs[r * 128 + n] + acc[i] + bo;
                    if (r & 1) v += gyb[((r - 1) >> 1) * 128 + n];
                    ob[r * 128 + n] = v;
                }
            }
        }
    }
}

extern "C" void kernel_launch(void* const* d_in, const int* in_sizes, int n_in,
                              void* d_out, int out_size, void* d_ws, size_t ws_size,
                              hipStream_t stream)
{
    (void)in_sizes; (void)n_in; (void)out_size; (void)ws_size;
    const float* x    = (const float*)d_in[0];
    const float* fcr  = (const float*)d_in[1];
    const float* fci  = (const float*)d_in[2];
    const float* g    = (const float*)d_in[3];
    const float* Wqkv = (const float*)d_in[4];
    const float* bqkv = (const float*)d_in[5];
    const float* Wout = (const float*)d_in[6];
    const float* bout = (const float*)d_in[7];
    const float* Wg   = (const float*)d_in[8];
    const float* bg   = (const float*)d_in[9];
    const float* Wr   = (const float*)d_in[10];
    const float* br   = (const float*)d_in[11];
    const float* Bb   = (const float*)d_in[12];
    float* out = (float*)d_out;

    char* wsb = (char*)d_ws;
    float* meanp = (float*)wsb;                         // 1 float (SUM of norms)
    float* norms = (float*)wsb + 64;                    // 81920 floats, ends @327936B
    bf16_t* wq  = (bf16_t*)(wsb + 328192);              // 49152 bf16
    bf16_t* wo  = wq + 49152;                           // 16384
    bf16_t* wgb = wo + 16384;                           // 16384
    bf16_t* wrb = wgb + 16384;                          // 16384 ; ws use ~525 KB

    hipMemsetAsync(meanp, 0, 4, stream);
    hipLaunchKernelGGL(k_wconv, dim3(384),   dim3(256), 0, stream, Wqkv, Wout, Wg, Wr, wq, wo, wgb, wrb);
    hipLaunchKernelGGL(k_norms, dim3(20480), dim3(256), 0, stream, x, g, norms);
    hipLaunchKernelGGL(k_mean,  dim3(80),    dim3(256), 0, stream, norms, meanp);
    hipLaunchKernelGGL(k_main,  dim3(NB),    dim3(256), 0, stream,
                       x, fcr, fci, g, bqkv, bout, bg, br, Bb, meanp, wq, wo, wgb, wrb, out);
}

// Round 5
// 376.115 us; speedup vs baseline: 2.8334x; 1.2745x over previous
//
#include <hip/hip_runtime.h>
#include <math.h>

#define NB   8192
#define NTOK 21
#define NP   10

typedef __bf16 bf16_t;
typedef __bf16 bf16x8 __attribute__((ext_vector_type(8)));
typedef __bf16 bf16x4 __attribute__((ext_vector_type(4)));
typedef float  f32x4  __attribute__((ext_vector_type(4)));

// swizzled element-index helpers (bf16 units; XOR at 8-element = 16B granularity)
#define ROW128(r,c) ((r)*128 + ((c) ^ (((r)&7)<<3)))   // [.][128] tiles, 256B rows
#define VTIDX(d,m)  ((d)*32  + ((m) ^ (((d)&3)<<3)))   // vt [128][32], 64B rows
#define ATIDX(r,m)  ((r)*32  + ((m) ^ (((r)&3)<<3)))   // attb rows, 64B rows

#define MFMA(a,b,c) __builtin_amdgcn_mfma_f32_16x16x32_bf16((a),(b),(c),0,0,0)

// ---------------- kernel 0: weights -> bf16, B-fragment layout [k>>3][n][8] ----------------
__global__ __launch_bounds__(256) void k_wconv(
    const float* __restrict__ Wqkv, const float* __restrict__ Wout,
    const float* __restrict__ Wg,   const float* __restrict__ Wr,
    bf16_t* __restrict__ wq, bf16_t* __restrict__ wo,
    bf16_t* __restrict__ wgb, bf16_t* __restrict__ wrb)
{
    int i = blockIdx.x * 256 + threadIdx.x;           // 0 .. 98303
    if (i < 49152) {
        int k = i / 384, n = i - k * 384;
        wq[((k >> 3) * 384 + n) * 8 + (k & 7)] = (bf16_t)Wqkv[i];
    } else {
        int j = i - 49152;
        int sel = j >> 14;                            // 0=Wout 1=Wg 2=Wr
        int t = j & 16383;
        int k = t >> 7, n = t & 127;
        const float* src = sel == 0 ? Wout : (sel == 1 ? Wg : Wr);
        bf16_t* dst = sel == 0 ? wo : (sel == 1 ? wgb : wrb);
        dst[((k >> 3) * 128 + n) * 8 + (k & 7)] = (bf16_t)src[t];
    }
}

// ---- kernel 1: per-patch-row norms of zc-rmsnorm(x); block partial -> 64 atomic slots ----
__global__ __launch_bounds__(256) void k_norms(const float* __restrict__ x,
                                               const float* __restrict__ g,
                                               float* __restrict__ part)
{
    __shared__ float sd[4];
    const int wave = threadIdx.x >> 6, lane = threadIdx.x & 63;
    const int row = blockIdx.x * 4 + wave;            // 0 .. 81919 (exact)
    const int b = row / NP, p = row - b * NP;
    const float* xr = x + (size_t)b * 2688 + (2 * p + 1) * 128;
    float a0 = xr[lane], a1 = xr[lane + 64];
    float s = a0 + a1, sq = a0 * a0 + a1 * a1;
    #pragma unroll
    for (int off = 32; off; off >>= 1) { s += __shfl_xor(s, off); sq += __shfl_xor(sq, off); }
    float mean = s * (1.0f / 128);
    float rstd = rsqrtf(sq * (1.0f / 128) - mean * mean + 1e-8f);
    float h0 = (a0 - mean) * rstd * g[lane];
    float h1 = (a1 - mean) * rstd * g[lane + 64];
    float n2 = h0 * h0 + h1 * h1;
    #pragma unroll
    for (int off = 32; off; off >>= 1) n2 += __shfl_xor(n2, off);
    if (lane == 0) sd[wave] = sqrtf(n2);
    __syncthreads();
    if (threadIdx.x == 0)
        atomicAdd(&part[(blockIdx.x & 63) * 16], sd[0] + sd[1] + sd[2] + sd[3]);
}

// ---------------- kernel 2: fused per-batch pipeline, bf16 MFMA, 4 blocks/CU ----------------
__global__ __launch_bounds__(256, 4) void k_main(
    const float* __restrict__ x,   const float* __restrict__ fcr,
    const float* __restrict__ fci, const float* __restrict__ g,
    const float* __restrict__ bqkv, const float* __restrict__ bout,
    const float* __restrict__ bg,   const float* __restrict__ br,
    const float* __restrict__ Bb,   const float* __restrict__ part,
    const bf16_t* __restrict__ wq,  const bf16_t* __restrict__ wo,
    const bf16_t* __restrict__ wgb, const bf16_t* __restrict__ wrb,
    float* __restrict__ out)
{
    __shared__ __align__(16) bf16_t hsb[32 * 128];      // normed bf16, swz; rows 21-31 = 0 (8K)
    __shared__ __align__(16) bf16_t reg1[32 * 128];     // qb -> attb[2][32][32]+att2e[2][16][32] (8K)
    __shared__ __align__(16) bf16_t reg2[32 * 128];     // kb -> yb (8K)
    __shared__ __align__(16) bf16_t reg3[128 * 32];     // vt[d][m] -> gyb f32[10][128] (8K)
    __shared__ __align__(16) char  pool[5376];          // fcs+fis | att[2][21][22]+att2 | y2bb[10][128]
    __shared__ float normv[11];                         // [0..9] patch norms, [10] global mean
    // total ~37.4 KB -> 4 blocks/CU

    float* fcs  = (float*)pool;            // [21*32] f32 (P2 only)
    float* fis  = (float*)pool + 672;      // [21*32] f32 (P2 only)
    float* att  = (float*)pool;            // [2][21][22] f32 (P4-P5b)
    float* att2 = (float*)(pool + 3696);   // [2][10][12] f32 (P4-P5b)
    bf16_t* y2bb = (bf16_t*)pool;          // [10][128] bf16 swz (P6-P7a)

    const int tid = threadIdx.x;
    const int w = tid >> 6, l = tid & 63, l15 = l & 15, gq = l >> 4;
    const int b = blockIdx.x;
    const float* xb = x + (size_t)b * 2688;

    // ---- P1: stage rope tables; zero hsb pads; zc-rmsnorm -> hsb; norms -> normv; mean ----
    {
        const float4* c4 = (const float4*)fcr; float4* dc = (float4*)fcs;
        const float4* i4 = (const float4*)fci; float4* di = (float4*)fis;
        if (tid < 168) { dc[tid] = c4[tid]; di[tid] = i4[tid]; }
        for (int i = tid; i < 11 * 128; i += 256)
            hsb[(21 + (i >> 7)) * 128 + (i & 127)] = (bf16_t)0.f;
        if (tid < 64) {
            float s = part[tid * 16];
            #pragma unroll
            for (int off = 32; off; off >>= 1) s += __shfl_xor(s, off);
            if (tid == 0) normv[10] = s * (1.f / 81920.f);
        }
        for (int r = w; r < 21; r += 4) {
            float a0 = xb[r * 128 + l], a1 = xb[r * 128 + 64 + l];
            float s = a0 + a1, sq = a0 * a0 + a1 * a1;
            #pragma unroll
            for (int off = 32; off; off >>= 1) { s += __shfl_xor(s, off); sq += __shfl_xor(sq, off); }
            float mean = s * (1.0f / 128);
            float rstd = rsqrtf(sq * (1.0f / 128) - mean * mean + 1e-8f);
            float h0 = (a0 - mean) * rstd * g[l];
            float h1 = (a1 - mean) * rstd * g[l + 64];
            hsb[ROW128(r, l)]      = (bf16_t)h0;
            hsb[ROW128(r, l + 64)] = (bf16_t)h1;
            if (r & 1) {
                float n2 = h0 * h0 + h1 * h1;
                #pragma unroll
                for (int off = 32; off; off >>= 1) n2 += __shfl_xor(n2, off);
                if (l == 0) normv[r >> 1] = sqrtf(n2);
            }
        }
    }
    __syncthreads();

    // ---- P2: qkv = h @ Wqkv + b (MFMA); rope q/k in-reg; scatter q->qb k->kb v->vt ----
    {
        bf16x8 afr[2][4];
        #pragma unroll
        for (int mt = 0; mt < 2; mt++)
            #pragma unroll
            for (int ks = 0; ks < 4; ks++)
                afr[mt][ks] = *(const bf16x8*)&hsb[ROW128(mt * 16 + l15, ks * 32 + gq * 8)];
        #pragma unroll 2
        for (int q6 = 0; q6 < 6; ++q6) {
            int nt = w * 6 + q6;
            int n = nt * 16 + l15;
            bf16x8 bfr[4];
            #pragma unroll
            for (int ks = 0; ks < 4; ks++)
                bfr[ks] = *(const bf16x8*)&wq[((ks * 4 + gq) * 384 + n) * 8];
            float bias = bqkv[n];
            #pragma unroll
            for (int mt = 0; mt < 2; mt++) {
                f32x4 acc = {0.f, 0.f, 0.f, 0.f};
                #pragma unroll
                for (int ks = 0; ks < 4; ks++) acc = MFMA(afr[mt][ks], bfr[ks], acc);
                int rbase = mt * 16 + gq * 4;
                if (n < 256) {                       // q or k: rope then store bf16
                    int d = n & 63, j = d >> 1;
                    bool ev = !(d & 1);
                    bf16_t* dst = (n < 128) ? reg1 : reg2;
                    int cc = n & 127;
                    #pragma unroll
                    for (int i = 0; i < 4; i++) {
                        int r = rbase + i; int rr = r < 21 ? r : 0;
                        float v = acc[i] + bias;
                        float p = __shfl_xor(v, 1);  // partner holds the pair's other half
                        float fr = fcs[rr * 32 + j], fi = fis[rr * 32 + j];
                        float o = ev ? (v * fr - p * fi) : (p * fi + v * fr);
                        dst[ROW128(r, cc)] = (bf16_t)o;
                    }
                } else {                             // v: store transposed vt[d][m]
                    int d = n - 256;
                    bf16x4 pv;
                    #pragma unroll
                    for (int i = 0; i < 4; i++) pv[i] = (bf16_t)(acc[i] + bias);
                    *(bf16x4*)&reg3[VTIDX(d, rbase)] = pv;
                }
            }
        }
    }
    __syncthreads();

    // ---- P4: scores via MFMA (att overwrites fcs/fis region - dead) ----
    {
        #pragma unroll
        for (int q2 = 0; q2 < 2; q2++) {
            int t = w * 2 + q2;                       // 8 full tiles
            int hh = t >> 2, mt = (t >> 1) & 1, nt = t & 1;
            f32x4 acc = {0.f, 0.f, 0.f, 0.f};
            #pragma unroll
            for (int ks = 0; ks < 2; ks++) {
                bf16x8 a  = *(const bf16x8*)&reg1[ROW128(mt * 16 + l15, hh * 64 + ks * 32 + gq * 8)];
                bf16x8 bb = *(const bf16x8*)&reg2[ROW128(nt * 16 + l15, hh * 64 + ks * 32 + gq * 8)];
                acc = MFMA(a, bb, acc);
            }
            int m = nt * 16 + l15;
            if (m < 21) {
                #pragma unroll
                for (int i = 0; i < 4; i++) {
                    int n = mt * 16 + gq * 4 + i;
                    if (n < 21) att[hh * 462 + n * 22 + m] = acc[i] * 0.125f + Bb[n * 21 + m];
                }
            }
        }
        if (w < 2) {                                  // 2 patch tiles (head = w)
            int hh = w;
            int ra = 2 * l15 + 1; if (ra > 20) ra = 20;
            int rb = 2 * l15;     if (rb > 20) rb = 20;
            f32x4 acc = {0.f, 0.f, 0.f, 0.f};
            #pragma unroll
            for (int ks = 0; ks < 2; ks++) {
                bf16x8 a  = *(const bf16x8*)&reg1[ROW128(ra, hh * 64 + ks * 32 + gq * 8)];
                bf16x8 bb = *(const bf16x8*)&reg2[ROW128(rb, hh * 64 + ks * 32 + gq * 8)];
                acc = MFMA(a, bb, acc);
            }
            int s = l15;
            if (s < 11) {
                #pragma unroll
                for (int i = 0; i < 4; i++) {
                    int p = gq * 4 + i;
                    if (p < 10) att2[hh * 120 + p * 12 + s] = acc[i] * 0.125f;
                }
            }
        }
    }
    __syncthreads();

    // ---- P5: softmax rows (fp32) ----
    if (tid < 42) {
        int hh = tid / 21, n = tid - hh * 21;
        float* row = &att[hh * 462 + n * 22];
        float mx = -1e30f;
        for (int m = 0; m < 21; m++) mx = fmaxf(mx, row[m]);
        float s = 0.f;
        for (int m = 0; m < 21; m++) { float e = __expf(row[m] - mx); row[m] = e; s += e; }
        float inv = 1.f / s;
        for (int m = 0; m < 21; m++) row[m] *= inv;
    } else if (tid >= 64 && tid < 84) {
        int t2 = tid - 64, hh = t2 / 10, p = t2 - hh * 10;
        float* row = &att2[hh * 120 + p * 12];
        float mx = -1e30f;
        for (int m = 0; m < 11; m++) mx = fmaxf(mx, row[m]);
        float s = 0.f;
        for (int m = 0; m < 11; m++) { float e = __expf(row[m] - mx); row[m] = e; s += e; }
        float inv = 1.f / s;
        for (int m = 0; m < 11; m++) row[m] *= inv;
    }
    __syncthreads();

    // ---- P5b: probs -> bf16 fragments (attb in qb region; att2e expanded to full keys) ----
    {
        bf16_t* attb  = reg1;            // [2][32][32], zero-padded
        bf16_t* att2e = reg1 + 2048;     // [2][16][32]: col m even -> att2[p][m/2], else 0
        for (int i = tid; i < 2048; i += 256) {
            int hh = i >> 10, r = (i >> 5) & 31, m = i & 31;
            float v = (r < 21 && m < 21) ? att[hh * 462 + r * 22 + m] : 0.f;
            attb[hh * 1024 + ATIDX(r, m)] = (bf16_t)v;
        }
        for (int i = tid; i < 1024; i += 256) {
            int hh = i >> 9, p = (i >> 5) & 15, m = i & 31;
            float v = (p < 10 && m < 21 && !(m & 1)) ? att2[hh * 120 + p * 12 + (m >> 1)] : 0.f;
            att2e[hh * 512 + ATIDX(p, m)] = (bf16_t)v;
        }
    }
    __syncthreads();

    // ---- P6: y = attb @ v (into yb = kb region); y2 = att2e @ v (y2bb overwrites att) ----
    {
        bf16_t* attb  = reg1;
        bf16_t* att2e = reg1 + 2048;
        for (int t = w * 6; t < w * 6 + 6; ++t) {     // 24 tiles: 16 y + 8 y2
            int hh, dloc, mt = 0, isY2;
            if (t < 16) { hh = t >> 3; mt = (t >> 2) & 1; dloc = hh * 64 + (t & 3) * 16 + l15; isY2 = 0; }
            else        { int u = t - 16; hh = u >> 2;    dloc = hh * 64 + (u & 3) * 16 + l15; isY2 = 1; }
            bf16x8 a;
            if (!isY2) { int r = mt * 16 + l15; a = *(const bf16x8*)&attb[hh * 1024 + ATIDX(r, gq * 8)]; }
            else       {                        a = *(const bf16x8*)&att2e[hh * 512 + ATIDX(l15, gq * 8)]; }
            bf16x8 bb = *(const bf16x8*)&reg3[VTIDX(dloc, gq * 8)];
            f32x4 acc = {0.f, 0.f, 0.f, 0.f};
            acc = MFMA(a, bb, acc);
            if (!isY2) {
                #pragma unroll
                for (int i = 0; i < 4; i++) reg2[ROW128(mt * 16 + gq * 4 + i, dloc)] = (bf16_t)acc[i];
            } else {
                #pragma unroll
                for (int i = 0; i < 4; i++) {
                    int rr2 = gq * 4 + i;
                    if (rr2 < 10) y2bb[ROW128(rr2, dloc)] = (bf16_t)acc[i];
                }
            }
        }
    }
    __syncthreads();

    // ---- P7a: gate & refine GEMMs; gy -> gyb (vt region, now dead) ----
    {
        float mn = normv[10];
        float* gyb = (float*)reg3;                    // [10][128] f32
        #pragma unroll
        for (int q2 = 0; q2 < 2; q2++) {
            int nt = w * 2 + q2;
            int n = nt * 16 + l15;
            int yrow = l15 < 10 ? l15 : 0;
            f32x4 accg = {0.f, 0.f, 0.f, 0.f}, accr = {0.f, 0.f, 0.f, 0.f};
            #pragma unroll
            for (int ks = 0; ks < 4; ks++) {
                bf16x8 wgf = *(const bf16x8*)&wgb[((ks * 4 + gq) * 128 + n) * 8];
                bf16x8 wrf = *(const bf16x8*)&wrb[((ks * 4 + gq) * 128 + n) * 8];
                bf16x8 ha  = *(const bf16x8*)&hsb[ROW128(2 * l15 + 1, ks * 32 + gq * 8)];
                bf16x8 ya  = *(const bf16x8*)&y2bb[ROW128(yrow, ks * 32 + gq * 8)];
                accg = MFMA(ha, wgf, accg);
                accr = MFMA(ya, wrf, accr);
            }
            float bgc = bg[n], brc = br[n];
            #pragma unroll
            for (int i = 0; i < 4; i++) {
                int p = gq * 4 + i;
                if (p < 10) {
                    float gate = 1.f / (1.f + __expf(-(accg[i] + bgc)));
                    float u = 1.f - 1.f / (1.f + __expf(-(normv[p] - mn)));
                    gyb[p * 128 + n] = u * gate * (accr[i] + brc);
                }
            }
        }
    }
    __syncthreads();

    // ---- P7b: out = x + y @ Wout + bout (+ gy on patch rows); x re-read from global ----
    {
        float* gyb = (float*)reg3;
        float* ob = out + (size_t)b * 2688;
        for (int t = w * 4; t < w * 4 + 4; ++t) {     // 16 tiles
            int mt = t >> 3, nt = t & 7;
            int n = nt * 16 + l15;
            f32x4 acc = {0.f, 0.f, 0.f, 0.f};
            #pragma unroll
            for (int ks = 0; ks < 4; ks++) {
                bf16x8 a  = *(const bf16x8*)&reg2[ROW128(mt * 16 + l15, ks * 32 + gq * 8)];
                bf16x8 wf = *(const bf16x8*)&wo[((ks * 4 + gq) * 128 + n) * 8];
                acc = MFMA(a, wf, acc);
            }
            float bo = bout[n];
            #pragma unroll
            for (int i = 0; i < 4; i++) {
                int r = mt * 16 + gq * 4 + i;
                if (r < 21) {
                    float v = xb[r * 128 + n] + acc[i] + bo;
                    if (r & 1) v += gyb[((r - 1) >> 1) * 128 + n];
                    ob[r * 128 + n] = v;
                }
            }
        }
    }
}

extern "C" void kernel_launch(void* const* d_in, const int* in_sizes, int n_in,
                              void* d_out, int out_size, void* d_ws, size_t ws_size,
                              hipStream_t stream)
{
    (void)in_sizes; (void)n_in; (void)out_size; (void)ws_size;
    const float* x    = (const float*)d_in[0];
    const float* fcr  = (const float*)d_in[1];
    const float* fci  = (const float*)d_in[2];
    const float* g    = (const float*)d_in[3];
    const float* Wqkv = (const float*)d_in[4];
    const float* bqkv = (const float*)d_in[5];
    const float* Wout = (const float*)d_in[6];
    const float* bout = (const float*)d_in[7];
    const float* Wg   = (const float*)d_in[8];
    const float* bg   = (const float*)d_in[9];
    const float* Wr   = (const float*)d_in[10];
    const float* br   = (const float*)d_in[11];
    const float* Bb   = (const float*)d_in[12];
    float* out = (float*)d_out;

    char* wsb = (char*)d_ws;
    float* part = (float*)wsb;                          // 64 slots x 16-float stride (4KB)
    bf16_t* wq  = (bf16_t*)(wsb + 4096);                // 49152 bf16
    bf16_t* wo  = wq + 49152;                           // 16384
    bf16_t* wgb = wo + 16384;                           // 16384
    bf16_t* wrb = wgb + 16384;                          // 16384 ; ws use ~200 KB

    hipMemsetAsync(part, 0, 4096, stream);
    hipLaunchKernelGGL(k_wconv, dim3(384),   dim3(256), 0, stream, Wqkv, Wout, Wg, Wr, wq, wo, wgb, wrb);
    hipLaunchKernelGGL(k_norms, dim3(20480), dim3(256), 0, stream, x, g, part);
    hipLaunchKernelGGL(k_main,  dim3(NB),    dim3(256), 0, stream,
                       x, fcr, fci, g, bqkv, bout, bg, br, Bb, part, wq, wo, wgb, wrb, out);
}

// Round 6
// 369.061 us; speedup vs baseline: 2.8875x; 1.0191x over previous
//
#include <hip/hip_runtime.h>
#include <math.h>

#define NB   8192
#define NTOK 21
#define NP   10

typedef __bf16 bf16_t;
typedef __bf16 bf16x8 __attribute__((ext_vector_type(8)));
typedef __bf16 bf16x4 __attribute__((ext_vector_type(4)));
typedef float  f32x4  __attribute__((ext_vector_type(4)));

// swizzled element-index helpers (bf16 units; XOR at 8-element = 16B granularity)
#define ROW128(r,c) ((r)*128 + ((c) ^ (((r)&7)<<3)))   // [.][128] tiles, 256B rows
#define VTIDX(d,m)  ((d)*32  + ((m) ^ (((d)&3)<<3)))   // vt [128][32], 64B rows
#define ATIDX(r,m)  ((r)*32  + ((m) ^ (((r)&3)<<3)))   // attb rows, 64B rows

#define MFMA(a,b,c) __builtin_amdgcn_mfma_f32_16x16x32_bf16((a),(b),(c),0,0,0)

// ---- kernel 1: blocks [0,384): weights -> bf16 B-fragment layout [k>>3][n][8]
//      blocks [384,2944): per-patch-row norms of zc-rmsnorm(x) -> 64 atomic slots
__global__ __launch_bounds__(256) void k_prep(
    const float* __restrict__ Wqkv, const float* __restrict__ Wout,
    const float* __restrict__ Wg,   const float* __restrict__ Wr,
    const float* __restrict__ x,    const float* __restrict__ g,
    bf16_t* __restrict__ wq, bf16_t* __restrict__ wo,
    bf16_t* __restrict__ wgb, bf16_t* __restrict__ wrb,
    float* __restrict__ part)
{
    __shared__ float sd[4];
    if (blockIdx.x < 384) {
        int i = blockIdx.x * 256 + threadIdx.x;       // 0 .. 98303
        if (i < 49152) {
            int k = i / 384, n = i - k * 384;
            wq[((k >> 3) * 384 + n) * 8 + (k & 7)] = (bf16_t)Wqkv[i];
        } else {
            int j = i - 49152;
            int sel = j >> 14;                        // 0=Wout 1=Wg 2=Wr
            int t = j & 16383;
            int k = t >> 7, n = t & 127;
            const float* src = sel == 0 ? Wout : (sel == 1 ? Wg : Wr);
            bf16_t* dst = sel == 0 ? wo : (sel == 1 ? wgb : wrb);
            dst[((k >> 3) * 128 + n) * 8 + (k & 7)] = (bf16_t)src[t];
        }
    } else {
        const int nb = blockIdx.x - 384;              // 0 .. 2559, 32 rows each
        const int wave = threadIdx.x >> 6, lane = threadIdx.x & 63;
        const float g0v = g[lane], g1v = g[lane + 64];
        float acc = 0.f;
        #pragma unroll
        for (int rr = 0; rr < 8; rr++) {
            int row = nb * 32 + wave * 8 + rr;        // 0 .. 81919
            int b = row / NP, p = row - b * NP;
            const float* xr = x + (size_t)b * 2688 + (2 * p + 1) * 128;
            float a0 = xr[lane], a1 = xr[lane + 64];
            float s = a0 + a1, sq = a0 * a0 + a1 * a1;
            #pragma unroll
            for (int off = 32; off; off >>= 1) { s += __shfl_xor(s, off); sq += __shfl_xor(sq, off); }
            float mean = s * (1.0f / 128);
            float rstd = rsqrtf(sq * (1.0f / 128) - mean * mean + 1e-8f);
            float h0 = (a0 - mean) * rstd * g0v;
            float h1 = (a1 - mean) * rstd * g1v;
            float n2 = h0 * h0 + h1 * h1;
            #pragma unroll
            for (int off = 32; off; off >>= 1) n2 += __shfl_xor(n2, off);
            if (lane == 0) acc += sqrtf(n2);
        }
        if (lane == 0) sd[wave] = acc;
        __syncthreads();
        if (threadIdx.x == 0)
            atomicAdd(&part[(nb & 63) * 16], sd[0] + sd[1] + sd[2] + sd[3]);
    }
}

// ---------------- kernel 2: fused per-batch pipeline, bf16 MFMA, 4 blocks/CU ----------------
__global__ __launch_bounds__(256, 4) void k_main(
    const float* __restrict__ x,   const float* __restrict__ fcr,
    const float* __restrict__ fci, const float* __restrict__ g,
    const float* __restrict__ bqkv, const float* __restrict__ bout,
    const float* __restrict__ bg,   const float* __restrict__ br,
    const float* __restrict__ Bb,   const float* __restrict__ part,
    const bf16_t* __restrict__ wq,  const bf16_t* __restrict__ wo,
    const bf16_t* __restrict__ wgb, const bf16_t* __restrict__ wrb,
    float* __restrict__ out)
{
    __shared__ __align__(16) bf16_t hsb[32 * 128];      // normed bf16, swz; rows 21-31 = 0 (8K)
    __shared__ __align__(16) bf16_t reg1[32 * 128];     // qb -> y2bb[10][128] (8K)
    __shared__ __align__(16) bf16_t reg2[32 * 128];     // kb -> yb (8K)
    __shared__ __align__(16) bf16_t reg3[128 * 32];     // vt[d][m] -> gyb f32[10][128] (8K)
    __shared__ __align__(16) char  pool[6144];          // fcs+fis (P2) | attb+att2e (P3'..P6)
    __shared__ float normv[11];                         // [0..9] patch norms, [10] global mean
    // total ~39.0 KB -> 4 blocks/CU

    float* fcs  = (float*)pool;            // [21*32] f32 (P2 only)
    float* fis  = (float*)pool + 672;      // [21*32] f32 (P2 only)

    const int tid = threadIdx.x;
    const int w = tid >> 6, l = tid & 63, l15 = l & 15, gq = l >> 4;
    const int b = blockIdx.x;
    const float* xb = x + (size_t)b * 2688;

    // ---- P1: stage rope tables; zero hsb pads; zc-rmsnorm -> hsb; norms -> normv; mean ----
    {
        const float4* c4 = (const float4*)fcr; float4* dc = (float4*)fcs;
        const float4* i4 = (const float4*)fci; float4* di = (float4*)fis;
        if (tid < 168) { dc[tid] = c4[tid]; di[tid] = i4[tid]; }
        for (int i = tid; i < 11 * 128; i += 256)
            hsb[(21 + (i >> 7)) * 128 + (i & 127)] = (bf16_t)0.f;
        if (tid < 64) {
            float s = part[tid * 16];
            #pragma unroll
            for (int off = 32; off; off >>= 1) s += __shfl_xor(s, off);
            if (tid == 0) normv[10] = s * (1.f / 81920.f);
        }
        for (int r = w; r < 21; r += 4) {
            float a0 = xb[r * 128 + l], a1 = xb[r * 128 + 64 + l];
            float s = a0 + a1, sq = a0 * a0 + a1 * a1;
            #pragma unroll
            for (int off = 32; off; off >>= 1) { s += __shfl_xor(s, off); sq += __shfl_xor(sq, off); }
            float mean = s * (1.0f / 128);
            float rstd = rsqrtf(sq * (1.0f / 128) - mean * mean + 1e-8f);
            float h0 = (a0 - mean) * rstd * g[l];
            float h1 = (a1 - mean) * rstd * g[l + 64];
            hsb[ROW128(r, l)]      = (bf16_t)h0;
            hsb[ROW128(r, l + 64)] = (bf16_t)h1;
            if (r & 1) {
                float n2 = h0 * h0 + h1 * h1;
                #pragma unroll
                for (int off = 32; off; off >>= 1) n2 += __shfl_xor(n2, off);
                if (l == 0) normv[r >> 1] = sqrtf(n2);
            }
        }
    }
    __syncthreads();

    // ---- P2: qkv = h @ Wqkv + b (MFMA); rope q/k in-reg; scatter q->reg1 k->reg2 v->vt ----
    {
        bf16x8 afr[2][4];
        #pragma unroll
        for (int mt = 0; mt < 2; mt++)
            #pragma unroll
            for (int ks = 0; ks < 4; ks++)
                afr[mt][ks] = *(const bf16x8*)&hsb[ROW128(mt * 16 + l15, ks * 32 + gq * 8)];
        #pragma unroll 2
        for (int q6 = 0; q6 < 6; ++q6) {
            int nt = w * 6 + q6;
            int n = nt * 16 + l15;
            bf16x8 bfr[4];
            #pragma unroll
            for (int ks = 0; ks < 4; ks++)
                bfr[ks] = *(const bf16x8*)&wq[((ks * 4 + gq) * 384 + n) * 8];
            float bias = bqkv[n];
            #pragma unroll
            for (int mt = 0; mt < 2; mt++) {
                f32x4 acc = {0.f, 0.f, 0.f, 0.f};
                #pragma unroll
                for (int ks = 0; ks < 4; ks++) acc = MFMA(afr[mt][ks], bfr[ks], acc);
                int rbase = mt * 16 + gq * 4;
                if (n < 256) {                       // q or k: rope then store bf16
                    int d = n & 63, j = d >> 1;
                    bool ev = !(d & 1);
                    bf16_t* dst = (n < 128) ? reg1 : reg2;
                    int cc = n & 127;
                    #pragma unroll
                    for (int i = 0; i < 4; i++) {
                        int r = rbase + i; int rr = r < 21 ? r : 0;
                        float v = acc[i] + bias;
                        float p = __shfl_xor(v, 1);  // partner holds the pair's other half
                        float fr = fcs[rr * 32 + j], fi = fis[rr * 32 + j];
                        float o = ev ? (v * fr - p * fi) : (p * fi + v * fr);
                        dst[ROW128(r, cc)] = (bf16_t)o;
                    }
                } else {                             // v: store transposed vt[d][m]
                    int d = n - 256;
                    bf16x4 pv;
                    #pragma unroll
                    for (int i = 0; i < 4; i++) pv[i] = (bf16_t)(acc[i] + bias);
                    *(bf16x4*)&reg3[VTIDX(d, rbase)] = pv;
                }
            }
        }
    }
    __syncthreads();

    // ---- P3': scores + IN-REGISTER softmax -> bf16 prob fragments in pool ----
    {
        bf16_t* attb  = (bf16_t*)pool;          // [2][32][32], fully covered incl. zero pad
        bf16_t* att2e = (bf16_t*)pool + 2048;   // [2][16][32], even cols hold patch probs
        // full attention: wave w -> head hh = w>>1, row-tile mt = w&1; cols l15 and 16+l15
        {
            const int hh = w >> 1, mt = w & 1;
            f32x4 acc0 = {0.f, 0.f, 0.f, 0.f}, acc1 = {0.f, 0.f, 0.f, 0.f};
            #pragma unroll
            for (int ks = 0; ks < 2; ks++) {
                bf16x8 a  = *(const bf16x8*)&reg1[ROW128(mt * 16 + l15, hh * 64 + ks * 32 + gq * 8)];
                bf16x8 b0 = *(const bf16x8*)&reg2[ROW128(l15,           hh * 64 + ks * 32 + gq * 8)];
                bf16x8 b1 = *(const bf16x8*)&reg2[ROW128(16 + l15,      hh * 64 + ks * 32 + gq * 8)];
                acc0 = MFMA(a, b0, acc0);
                acc1 = MFMA(a, b1, acc1);
            }
            const int m0 = l15, m1 = 16 + l15;
            const bool c1 = (m1 < 21);
            #pragma unroll
            for (int i = 0; i < 4; i++) {
                int r = mt * 16 + gq * 4 + i;
                int rr = r < 21 ? r : 0;
                float v0 = acc0[i] * 0.125f + Bb[rr * 21 + m0];
                float v1 = c1 ? acc1[i] * 0.125f + Bb[rr * 21 + m1] : -1e30f;
                float mx = fmaxf(v0, v1);
                #pragma unroll
                for (int off = 8; off; off >>= 1) mx = fmaxf(mx, __shfl_xor(mx, off));
                float e0 = __expf(v0 - mx);
                float e1 = c1 ? __expf(v1 - mx) : 0.f;
                float s = e0 + e1;
                #pragma unroll
                for (int off = 8; off; off >>= 1) s += __shfl_xor(s, off);
                float is = 1.f / s;
                bool rv = (r < 21);
                attb[hh * 1024 + ATIDX(r, m0)] = (bf16_t)(rv ? e0 * is : 0.f);
                attb[hh * 1024 + ATIDX(r, m1)] = (bf16_t)(rv ? e1 * is : 0.f);
            }
        }
        // patch/stat attention: waves 0,2 -> head w>>1
        if ((w & 1) == 0) {
            const int hh = w >> 1;
            int ra = 2 * l15 + 1; if (ra > 20) ra = 20;
            int rb = 2 * l15;     if (rb > 20) rb = 20;
            f32x4 acc = {0.f, 0.f, 0.f, 0.f};
            #pragma unroll
            for (int ks = 0; ks < 2; ks++) {
                bf16x8 a  = *(const bf16x8*)&reg1[ROW128(ra, hh * 64 + ks * 32 + gq * 8)];
                bf16x8 bb = *(const bf16x8*)&reg2[ROW128(rb, hh * 64 + ks * 32 + gq * 8)];
                acc = MFMA(a, bb, acc);
            }
            const bool cv = (l15 < 11);
            #pragma unroll
            for (int i = 0; i < 4; i++) {
                int p = gq * 4 + i;
                float v = cv ? acc[i] * 0.125f : -1e30f;
                float mx = v;
                #pragma unroll
                for (int off = 8; off; off >>= 1) mx = fmaxf(mx, __shfl_xor(mx, off));
                float e = cv ? __expf(v - mx) : 0.f;
                float s = e;
                #pragma unroll
                for (int off = 8; off; off >>= 1) s += __shfl_xor(s, off);
                float is = 1.f / s;
                att2e[hh * 512 + ATIDX(p, 2 * l15)]     = (bf16_t)((p < 10) ? e * is : 0.f);
                att2e[hh * 512 + ATIDX(p, 2 * l15 + 1)] = (bf16_t)0.f;
            }
        }
    }
    __syncthreads();

    // ---- P6: y = attb @ v (into reg2); y2 = att2e @ v (into y2bb = reg1, q dead) ----
    {
        bf16_t* attb  = (bf16_t*)pool;
        bf16_t* att2e = (bf16_t*)pool + 2048;
        bf16_t* y2bb  = reg1;                         // [10][128] bf16 swz
        for (int t = w * 6; t < w * 6 + 6; ++t) {     // 24 tiles: 16 y + 8 y2
            int hh, dloc, mt = 0, isY2;
            if (t < 16) { hh = t >> 3; mt = (t >> 2) & 1; dloc = hh * 64 + (t & 3) * 16 + l15; isY2 = 0; }
            else        { int u = t - 16; hh = u >> 2;    dloc = hh * 64 + (u & 3) * 16 + l15; isY2 = 1; }
            bf16x8 a;
            if (!isY2) { int r = mt * 16 + l15; a = *(const bf16x8*)&attb[hh * 1024 + ATIDX(r, gq * 8)]; }
            else       {                        a = *(const bf16x8*)&att2e[hh * 512 + ATIDX(l15, gq * 8)]; }
            bf16x8 bb = *(const bf16x8*)&reg3[VTIDX(dloc, gq * 8)];
            f32x4 acc = {0.f, 0.f, 0.f, 0.f};
            acc = MFMA(a, bb, acc);
            if (!isY2) {
                #pragma unroll
                for (int i = 0; i < 4; i++) reg2[ROW128(mt * 16 + gq * 4 + i, dloc)] = (bf16_t)acc[i];
            } else {
                #pragma unroll
                for (int i = 0; i < 4; i++) {
                    int rr2 = gq * 4 + i;
                    if (rr2 < 10) y2bb[ROW128(rr2, dloc)] = (bf16_t)acc[i];
                }
            }
        }
    }
    __syncthreads();

    // ---- P7a: gate & refine GEMMs; gy -> gyb (vt region, now dead) ----
    {
        bf16_t* y2bb = reg1;
        float mn = normv[10];
        float* gyb = (float*)reg3;                    // [10][128] f32
        #pragma unroll
        for (int q2 = 0; q2 < 2; q2++) {
            int nt = w * 2 + q2;
            int n = nt * 16 + l15;
            int yrow = l15 < 10 ? l15 : 0;
            f32x4 accg = {0.f, 0.f, 0.f, 0.f}, accr = {0.f, 0.f, 0.f, 0.f};
            #pragma unroll
            for (int ks = 0; ks < 4; ks++) {
                bf16x8 wgf = *(const bf16x8*)&wgb[((ks * 4 + gq) * 128 + n) * 8];
                bf16x8 wrf = *(const bf16x8*)&wrb[((ks * 4 + gq) * 128 + n) * 8];
                bf16x8 ha  = *(const bf16x8*)&hsb[ROW128(2 * l15 + 1, ks * 32 + gq * 8)];
                bf16x8 ya  = *(const bf16x8*)&y2bb[ROW128(yrow, ks * 32 + gq * 8)];
                accg = MFMA(ha, wgf, accg);
                accr = MFMA(ya, wrf, accr);
            }
            float bgc = bg[n], brc = br[n];
            #pragma unroll
            for (int i = 0; i < 4; i++) {
                int p = gq * 4 + i;
                if (p < 10) {
                    float gate = 1.f / (1.f + __expf(-(accg[i] + bgc)));
                    float u = 1.f - 1.f / (1.f + __expf(-(normv[p] - mn)));
                    gyb[p * 128 + n] = u * gate * (accr[i] + brc);
                }
            }
        }
    }
    __syncthreads();

    // ---- P7b: out = x + y @ Wout + bout (+ gy on patch rows); x re-read from global ----
    {
        float* gyb = (float*)reg3;
        float* ob = out + (size_t)b * 2688;
        for (int t = w * 4; t < w * 4 + 4; ++t) {     // 16 tiles
            int mt = t >> 3, nt = t & 7;
            int n = nt * 16 + l15;
            f32x4 acc = {0.f, 0.f, 0.f, 0.f};
            #pragma unroll
            for (int ks = 0; ks < 4; ks++) {
                bf16x8 a  = *(const bf16x8*)&reg2[ROW128(mt * 16 + l15, ks * 32 + gq * 8)];
                bf16x8 wf = *(const bf16x8*)&wo[((ks * 4 + gq) * 128 + n) * 8];
                acc = MFMA(a, wf, acc);
            }
            float bo = bout[n];
            #pragma unroll
            for (int i = 0; i < 4; i++) {
                int r = mt * 16 + gq * 4 + i;
                if (r < 21) {
                    float v = xb[r * 128 + n] + acc[i] + bo;
                    if (r & 1) v += gyb[((r - 1) >> 1) * 128 + n];
                    ob[r * 128 + n] = v;
                }
            }
        }
    }
}

extern "C" void kernel_launch(void* const* d_in, const int* in_sizes, int n_in,
                              void* d_out, int out_size, void* d_ws, size_t ws_size,
                              hipStream_t stream)
{
    (void)in_sizes; (void)n_in; (void)out_size; (void)ws_size;
    const float* x    = (const float*)d_in[0];
    const float* fcr  = (const float*)d_in[1];
    const float* fci  = (const float*)d_in[2];
    const float* g    = (const float*)d_in[3];
    const float* Wqkv = (const float*)d_in[4];
    const float* bqkv = (const float*)d_in[5];
    const float* Wout = (const float*)d_in[6];
    const float* bout = (const float*)d_in[7];
    const float* Wg   = (const float*)d_in[8];
    const float* bg   = (const float*)d_in[9];
    const float* Wr   = (const float*)d_in[10];
    const float* br   = (const float*)d_in[11];
    const float* Bb   = (const float*)d_in[12];
    float* out = (float*)d_out;

    char* wsb = (char*)d_ws;
    float* part = (float*)wsb;                          // 64 slots x 16-float stride (4KB)
    bf16_t* wq  = (bf16_t*)(wsb + 4096);                // 49152 bf16
    bf16_t* wo  = wq + 49152;                           // 16384
    bf16_t* wgb = wo + 16384;                           // 16384
    bf16_t* wrb = wgb + 16384;                          // 16384 ; ws use ~200 KB

    hipMemsetAsync(part, 0, 4096, stream);
    hipLaunchKernelGGL(k_prep, dim3(2944), dim3(256), 0, stream,
                       Wqkv, Wout, Wg, Wr, x, g, wq, wo, wgb, wrb, part);
    hipLaunchKernelGGL(k_main, dim3(NB),   dim3(256), 0, stream,
                       x, fcr, fci, g, bqkv, bout, bg, br, Bb, part, wq, wo, wgb, wrb, out);
}